// Round 3
// baseline (219.459 us; speedup 1.0000x reference)
//
#include <hip/hip_runtime.h>
#include <hip/hip_bf16.h>
#include <math.h>

typedef __hip_bfloat16 bf16;
typedef __attribute__((ext_vector_type(8))) short frag8;
typedef __attribute__((ext_vector_type(4))) float f32x4;
typedef __attribute__((ext_vector_type(16))) float f32x16;
typedef __attribute__((ext_vector_type(2))) unsigned int u32x2;
typedef __attribute__((ext_vector_type(4))) unsigned int u32x4;

#define HW  1296
#define CH  128
#define TT  1327104   // 8 * 1296 * 128

__device__ __forceinline__ float b2f(bf16 v) { return __bfloat162float(v); }
__device__ __forceinline__ float bits2f(unsigned short u) {
    return __uint_as_float(((unsigned)u) << 16);
}
__device__ __forceinline__ float frcp(float x) { return __builtin_amdgcn_rcpf(x); }
__device__ __forceinline__ float fsigm(float x) { return frcp(1.0f + __expf(-x)); }
__device__ __forceinline__ float ftanh(float x) {
    float xc = fminf(15.0f, fmaxf(-15.0f, x));
    float e = __expf(2.0f * xc);
    return (e - 1.0f) * frcp(e + 1.0f);
}
// round-half-up f32->bf16 pair pack: 2 adds + 1 v_perm
__device__ __forceinline__ int packrh(float a, float b) {
    unsigned ua = __float_as_uint(a) + 0x8000u;
    unsigned ub = __float_as_uint(b) + 0x8000u;
    return (int)__builtin_amdgcn_perm(ub, ua, 0x07060302);
}
__device__ __forceinline__ int2 pack4(float a, float b, float c, float d) {
    int2 r; r.x = packrh(a, b); r.y = packrh(c, d); return r;
}
// packed RNE f32 pair -> bf16x2 in one VALU op
__device__ __forceinline__ unsigned cvtpk(float a, float b) {
    unsigned r;
    asm("v_cvt_pk_bf16_f32 %0, %1, %2" : "=v"(r) : "v"(a), "v"(b));
    return r;
}

// inline wave-uniform dtype detection (256 probe elems of w_in)
__device__ __forceinline__ int detect_f32(const void* w) {
    const short4* p = (const short4*)w;
    short4 v = p[threadIdx.x & 63];
    int bad = 0;
    #pragma unroll
    for (int j = 0; j < 4; ++j) {
        float f = bits2f(((const unsigned short*)&v)[j]);
        if (!(fabsf(f) <= 100.0f)) bad = 1;   // catches NaN/Inf too
    }
    return __any(bad) ? 1 : 0;
}

// ---------------- weight prep ----------------
// Wst (bf16): w_in[128o][128i]@0 | wconvT[9tap][128o][128r]@16384 |
//   wqkv[384o][128i]@163840 | wg[3][128o][256k]@212992 | wout[128o][128i]@311296
// Bst f32[768]: in@0 conv@128 i@256 g@384 o@512 out@640
// NOTE: wq rows (idx 163840..180223) are pre-scaled by log2(e) so attention
// can use exp2 directly (Qb feeds only k_attn).
__global__ __launch_bounds__(256) void k_prep(
    const void* w_in, const void* w_conv, const void* wq, const void* wk, const void* wv,
    const void* w_i, const void* w_g, const void* w_o, const void* w_out,
    const void* b_in, const void* b_conv, const void* b_i, const void* b_g,
    const void* b_o, const void* b_out,
    bf16* __restrict__ Wdst, float* __restrict__ Bdst)
{
    int idx = blockIdx.x * 256 + threadIdx.x;
    const int f = detect_f32(w_in);
    if (idx < 327680) {
        const void* src; int si;
        if (idx < 16384)       { src = w_in; si = idx; }   // native [o][i]
        else if (idx < 163840) { int j = idx - 16384; int tap = j >> 14, rem = j & 16383;
                                 int o = rem >> 7, r = rem & 127;
                                 src = w_conv; si = o * 2304 + r * 9 + tap; }
        else if (idx < 212992) { int j = idx - 163840; int o = j >> 7, i = j & 127;
                                 int ws_ = o >> 7;
                                 src = ws_ == 0 ? wq : ws_ == 1 ? wk : wv;
                                 si = (o & 127) * 128 + i; }
        else if (idx < 311296) { int j = idx - 212992; int g = j >> 15, rem = j & 32767;
                                 int o = rem >> 8, k = rem & 255;
                                 src = g == 0 ? w_i : g == 1 ? w_g : w_o; si = o * 256 + k; }
        else                   { int j = idx - 311296; int o = j >> 7, i = j & 127;
                                 src = w_out; si = o * 128 + i; }
        float v = f ? ((const float*)src)[si] : b2f(((const bf16*)src)[si]);
        if (idx >= 163840 && idx < 180224) v *= 1.4426950408889634f;  // wq * log2(e)
        Wdst[idx] = __float2bfloat16(v);
    } else if (idx < 327680 + 768) {
        int j = idx - 327680; int b = j >> 7, e = j & 127;
        const void* src = b == 0 ? b_in : b == 1 ? b_conv : b == 2 ? b_i
                        : b == 3 ? b_g : b == 4 ? b_o : b_out;
        Bdst[j] = f ? ((const float*)src)[e] : b2f(((const bf16*)src)[e]);
    }
}

// ---------------- k_inm: fused transpose + MFMA GEMM + tanh ----------------
// grid (8 n, 41 ptile, 4 otile) — n on blockIdx.x => all blocks of a batch land
// on one XCD (linear wg id % 8 == n), keeping the activation slab in one L2.
__global__ __launch_bounds__(256) void k_inm(const void* __restrict__ x,
                                             const void* __restrict__ wraw,
                                             const bf16* __restrict__ Wm,   // [o][i]
                                             const float* __restrict__ bias,
                                             bf16* __restrict__ XT) {
    __shared__ short Xl[32][132];
    const int tid = threadIdx.x, wave = tid >> 6, lane = tid & 63;
    const int quad = lane >> 4, l16 = lane & 15;
    const int n = blockIdx.x;
    const int pbase = blockIdx.y * 32;
    const int obase = blockIdx.z * 32 + (wave & 1) * 16;
    const int pstrip = (wave >> 1) * 16;
    const int f = detect_f32(wraw);

    #pragma unroll
    for (int rep = 0; rep < 4; ++rep) {
        int u = tid + rep * 256;
        int i = u >> 3;
        int p4 = (u & 7) * 4;
        int p = pbase + p4;
        short4 s = {0, 0, 0, 0};
        if (p < HW) {
            size_t gi = (size_t)n * CH * HW + (size_t)i * HW + p;
            if (f) {
                float4 fv = *(const float4*)((const float*)x + gi);
                int2 pk = pack4(fv.x, fv.y, fv.z, fv.w);
                s = *(short4*)&pk;
            } else {
                s = *(const short4*)((const bf16*)x + gi);
            }
        }
        Xl[p4 + 0][i] = s.x; Xl[p4 + 1][i] = s.y;
        Xl[p4 + 2][i] = s.z; Xl[p4 + 3][i] = s.w;
    }
    __syncthreads();

    const int pl = pstrip + l16;
    f32x4 acc = {0.f, 0.f, 0.f, 0.f};
    #pragma unroll
    for (int kc = 0; kc < 4; ++kc) {
        int k = kc * 32 + quad * 8;
        short4 b0 = *(const short4*)&Xl[pl][k];
        short4 b1 = *(const short4*)&Xl[pl][k + 4];
        frag8 bf = {b0.x, b0.y, b0.z, b0.w, b1.x, b1.y, b1.z, b1.w};
        frag8 wf = *(const frag8*)&Wm[(obase + l16) * CH + k];
        acc = __builtin_amdgcn_mfma_f32_16x16x32_bf16(wf, bf, acc, 0, 0, 0);
    }

    int p = pbase + pstrip + l16;
    if (p < HW) {
        int og = obase + quad * 4;
        int2 pk = pack4(ftanh(acc[0] + bias[og + 0]), ftanh(acc[1] + bias[og + 1]),
                        ftanh(acc[2] + bias[og + 2]), ftanh(acc[3] + bias[og + 3]));
        *(int2*)((short*)XT + ((size_t)n * HW + p) * CH + og) = pk;
    }
}

// ---------------- MFMA GEMM family, 32p x 32o blocks (wave = 16o x 16p, 1 p-frag) ------
// grid (8 n, 41 ptile, z otile) — XCD-local per batch. p-split doubles wave supply
// (latency-bound at 2.6 waves/SIMD before; now ~5.1+/SIMD).
// MODE 0: CONV (9 taps, unrolled)  MODE 1: QKV (Q,K head-grouped; V channel-first via swap)
// MODE 2: GATES (K=256, fused cell)
template<int MODE>
__global__ __launch_bounds__(256) void k_mm(
    const bf16* __restrict__ Act, const bf16* __restrict__ Act2,
    const bf16* __restrict__ Wm, const float* __restrict__ bias,
    bf16* __restrict__ o0, bf16* __restrict__ o1, bf16* __restrict__ o2)
{
    constexpr int NW  = (MODE == 2) ? 3 : 1;
    constexpr int KW  = (MODE == 2) ? 256 : 128;
    const int tid = threadIdx.x, wave = tid >> 6, lane = tid & 63;
    const int quad = lane >> 4, l16 = lane & 15;
    const int ostrip = wave & 1, pstrip = wave >> 1;
    const int n = blockIdx.x;
    const int obase = blockIdx.z * 32 + ostrip * 16;
    const int pbase = blockIdx.y * 32 + pstrip * 16;
    const bf16* actn = Act + (size_t)n * HW * CH;
    const bool vtile = (MODE == 1) && (obase >= 256);   // wave-uniform

    const int p1 = pbase + l16;
    const bool p1ok = p1 < HW;

    frag8 zf = {0, 0, 0, 0, 0, 0, 0, 0};
    f32x4 acc[NW];
    #pragma unroll
    for (int g = 0; g < NW; ++g) acc[g] = (f32x4){0.f, 0.f, 0.f, 0.f};

    if (MODE == 0) {
        const int h1 = p1 / 36, w1 = p1 - h1 * 36;
        #pragma unroll
        for (int tap = 0; tap < 9; ++tap) {
            int dy = tap / 3 - 1, dx = tap - (tap / 3) * 3 - 1;
            bool ok1 = p1ok && (unsigned)(h1 + dy) < 36u && (unsigned)(w1 + dx) < 36u;
            int sh = dy * 36 + dx;
            const bf16* a1 = actn + (size_t)(p1 + sh) * CH + quad * 8;
            const bf16* wp = Wm + tap * 16384 + (obase + l16) * CH + quad * 8;
            #pragma unroll
            for (int kc = 0; kc < 4; ++kc) {
                frag8 bf1 = zf;
                if (ok1) bf1 = *(const frag8*)&a1[kc * 32];
                frag8 wf = *(const frag8*)&wp[kc * 32];
                acc[0] = __builtin_amdgcn_mfma_f32_16x16x32_bf16(wf, bf1, acc[0], 0, 0, 0);
            }
        }
    } else {
        const bf16* act2n = (MODE == 2) ? Act2 + (size_t)n * HW * CH : nullptr;
        #pragma unroll
        for (int kc = 0; kc < KW / 32; ++kc) {
            const bf16* src = (MODE == 2 && kc >= 4) ? act2n : actn;
            int ko = (MODE == 2 ? (kc & 3) : kc) * 32 + quad * 8;
            frag8 bf1 = zf;
            if (p1ok) bf1 = *(const frag8*)&src[(size_t)p1 * CH + ko];
            #pragma unroll
            for (int g = 0; g < NW; ++g) {
                const bf16* wp = Wm + g * 32768 + (obase + l16) * KW + kc * 32 + quad * 8;
                frag8 wf = *(const frag8*)wp;
                if (vtile) {
                    acc[g] = __builtin_amdgcn_mfma_f32_16x16x32_bf16(bf1, wf, acc[g], 0, 0, 0);
                } else {
                    acc[g] = __builtin_amdgcn_mfma_f32_16x16x32_bf16(wf, bf1, acc[g], 0, 0, 0);
                }
            }
        }
    }

    // ---- epilogue ----
    if (vtile) {
        int ov = (obase - 256) + l16;
        int p4 = pbase + quad * 4;
        if (p4 < HW) {
            int2 pk = pack4(acc[0][0], acc[0][1], acc[0][2], acc[0][3]);
            *(int2*)((short*)o2 + ((size_t)n * CH + ov) * HW + p4) = pk;
        }
        return;
    }
    const int og = obase + quad * 4;
    const int p = pbase + l16;
    if (p >= HW) return;
    size_t rowoff = ((size_t)n * HW + p) * CH;
    if (MODE == 0) {
        int2 pk = pack4(acc[0][0] + bias[og + 0], acc[0][1] + bias[og + 1],
                        acc[0][2] + bias[og + 2], acc[0][3] + bias[og + 3]);
        *(int2*)((short*)o0 + rowoff + og) = pk;
    } else if (MODE == 1) {
        int which = og >> 7, ol = og & 127;
        bf16* dst = which == 0 ? o0 : o1;
        size_t di = (((size_t)n * 8 + (ol >> 4)) * HW + p) * 16 + (ol & 15);
        int2 pk = pack4(acc[0][0], acc[0][1], acc[0][2], acc[0][3]);
        *(int2*)((short*)dst + di) = pk;
    } else {
        float hv[4];
        #pragma unroll
        for (int r = 0; r < 4; ++r) {
            int o = og + r;
            float iv = fsigm(acc[0][r] + bias[o]);
            float gv = ftanh(acc[1][r] + bias[128 + o]);
            float ov = fsigm(acc[2][r] + bias[256 + o]);
            hv[r] = ov * ftanh(iv * gv);
        }
        int2 pk = pack4(hv[0], hv[1], hv[2], hv[3]);
        *(int2*)((short*)o0 + rowoff + og) = pk;
    }
}

// ---------------- k_outm: out[n][o][p] = W_out h + b (channel-first store) ----------------
// grid (8 n, 41 ptile, 2 otile)
__global__ __launch_bounds__(256) void k_outm(const bf16* __restrict__ Hb,
                                              const bf16* __restrict__ Wm,
                                              const float* __restrict__ bias,
                                              void* __restrict__ out,
                                              const void* __restrict__ wraw) {
    const int tid = threadIdx.x, wave = tid >> 6, lane = tid & 63;
    const int quad = lane >> 4, l16 = lane & 15;
    const int pstrip = wave & 1, ostrip = wave >> 1;
    const int n = blockIdx.x;
    const int pbase = blockIdx.y * 32 + pstrip * 16;
    const int obase = blockIdx.z * 64 + ostrip * 32;
    if (pbase >= HW) return;
    const int f32f = detect_f32(wraw);
    const bf16* hn = Hb + (size_t)n * HW * CH;
    const int pa = pbase + l16;

    f32x4 acc0 = {0.f, 0.f, 0.f, 0.f}, acc1 = {0.f, 0.f, 0.f, 0.f};
    #pragma unroll
    for (int kc = 0; kc < 4; ++kc) {
        int ko = kc * 32 + quad * 8;
        frag8 af = *(const frag8*)&hn[(size_t)pa * CH + ko];
        frag8 b0 = *(const frag8*)&Wm[(obase + l16) * CH + ko];
        frag8 b1 = *(const frag8*)&Wm[(obase + 16 + l16) * CH + ko];
        acc0 = __builtin_amdgcn_mfma_f32_16x16x32_bf16(af, b0, acc0, 0, 0, 0);
        acc1 = __builtin_amdgcn_mfma_f32_16x16x32_bf16(af, b1, acc1, 0, 0, 0);
    }
    int p4 = pbase + quad * 4;
    #pragma unroll
    for (int ot = 0; ot < 2; ++ot) {
        int o = obase + ot * 16 + l16;
        f32x4 a = ot ? acc1 : acc0;
        float bv = bias[o];
        size_t di = ((size_t)n * CH + o) * HW + p4;
        if (f32f) {
            float4 fv = {a[0] + bv, a[1] + bv, a[2] + bv, a[3] + bv};
            *(float4*)&((float*)out)[di] = fv;
        } else {
            int2 pk = pack4(a[0] + bv, a[1] + bv, a[2] + bv, a[3] + bv);
            *(int2*)&((short*)out)[di] = pk;
        }
    }
}

// ---------------- MFMA flash attention v7: 32x32x16, d-split x2, S-pipelined ----------------
// grid (8 n, 11 qtile, 8 head), 512 threads = 8 waves: qw = w&3 (32 q each),
// dq = w>>2 (d-halves: chunks 0..19 / 20..40). Softmax has no running max, so
// partial O = sum P*V and L = sum P over disjoint d-ranges combine additively
// (LDS, one barrier). Per chunk the NEXT chunk's QK^T MFMA issues before the
// current chunk's exp2/pack, and K is prefetched 2 chunks deep — the serial
// chain per chunk is VALU+PV only.
// S layout (m74/m101): col=q=lane&31, row=d_local=(r&3)+8*(r>>2)+4*(lane>>5).
// lsum comes free: V A-operand row c==16 is all-ones -> Oacc[8] = sum_d P[d][q].
// wq pre-scaled by log2(e) in k_prep -> P = exp2(S) directly.
__global__ __launch_bounds__(512) void k_attn(const bf16* __restrict__ Qg,
                                              const bf16* __restrict__ Kg,
                                              const bf16* __restrict__ Vcf,
                                              bf16* __restrict__ A) {
    __shared__ float Lc[4][9][64];   // [qw][acc reg 0..7 + lsum][lane] — conflict-free

    const int tid = threadIdx.x;
    const int w = tid >> 6, lane = tid & 63;
    const int l32 = lane & 31, hi = lane >> 5;
    const int qw = w & 3, dq = w >> 2;
    const int n = blockIdx.x;
    const int head = blockIdx.z;
    const int qb = blockIdx.y * 128 + qw * 32;
    const int qtok = qb + l32;

    const short* Qh = (const short*)Qg + ((size_t)(n * 8 + head)) * HW * 16;
    const short* Kh = (const short*)Kg + ((size_t)(n * 8 + head)) * HW * 16;
    const short* Vh = (const short*)Vcf + ((size_t)n * CH + head * 16) * HW;

    // Q fragment (B operand): B[c = 8*hi + j][q = l32]; OOB q-waves compute
    // garbage on qf=0 but must NOT exit (barrier below).
    frag8 qf = {0, 0, 0, 0, 0, 0, 0, 0};
    if (qtok < HW) qf = *(const frag8*)&Qh[(size_t)qtok * 16 + hi * 8];

    // V A-operand fill: row c==16 -> ones (lsum row), rows 17..31 -> zero
    const short one = (short)0x3F80;
    const frag8 vones = {one, one, one, one, one, one, one, one};
    const frag8 vzero = {0, 0, 0, 0, 0, 0, 0, 0};
    const frag8 vfill = (l32 == 16) ? vones : vzero;
    const bool vload = l32 < 16;
    const short* Vrow = Vh + (size_t)(vload ? l32 : 0) * HW;

    const f32x16 zero16 = {};
    f32x16 Oacc = {};

    auto KLD = [&](int dd) -> frag8 {
        return *(const frag8*)&Kh[(size_t)(dd + l32) * 16 + hi * 8];
    };
    auto VLD = [&](int dd) -> frag8 {
        return vload ? *(const frag8*)&Vrow[dd + hi * 8] : vfill;
    };

    const int c0 = dq ? 20 : 0;       // chunk range: dq0 -> 0..19, dq1 -> 20..39 (+tail 40)
    frag8 kf  = KLD(c0 * 32);         // K(chunk c0)
    frag8 kf2 = KLD(c0 * 32 + 32);    // K(chunk c0+1)
    frag8 va  = VLD(c0 * 32);
    frag8 vb  = VLD(c0 * 32 + 16);
    f32x16 S = __builtin_amdgcn_mfma_f32_32x32x16_bf16(kf, qf, zero16, 0, 0, 0);

    // 20 chunks per wave. Prefetch: K 2-deep, V 1-deep. Reads past logical end
    // stay inside the workspace (spill into adjacent buffers, values unused).
    for (int it = 0; it < 20; ++it) {
        const int d0 = (c0 + it) * 32;
        frag8 kn  = KLD(d0 + 64);
        frag8 van = VLD(d0 + 32);
        frag8 vbn = VLD(d0 + 48);
        // issue next chunk's QK^T early; its latency hides under the VALU below.
        // dq1 it=19: this computes the tail chunk's S (rows 0..7 valid) — used below.
        f32x16 Sn = __builtin_amdgcn_mfma_f32_32x32x16_bf16(kf2, qf, zero16, 0, 0, 0);

        float p[16];
        #pragma unroll
        for (int r = 0; r < 16; ++r) p[r] = __builtin_amdgcn_exp2f(S[r]);

        #pragma unroll
        for (int hh = 0; hh < 2; ++hh) {
            unsigned P0 = cvtpk(p[hh * 8 + 0], p[hh * 8 + 1]);
            unsigned P1 = cvtpk(p[hh * 8 + 2], p[hh * 8 + 3]);
            unsigned P2 = cvtpk(p[hh * 8 + 4], p[hh * 8 + 5]);
            unsigned P3 = cvtpk(p[hh * 8 + 6], p[hh * 8 + 7]);
            u32x2 s02 = __builtin_amdgcn_permlane32_swap(P0, P2, false, false);
            u32x2 s13 = __builtin_amdgcn_permlane32_swap(P1, P3, false, false);
            u32x4 bw = {s02[0], s13[0], s02[1], s13[1]};
            frag8 pf = __builtin_bit_cast(frag8, bw);
            Oacc = __builtin_amdgcn_mfma_f32_32x32x16_bf16(hh ? vb : va, pf, Oacc, 0, 0, 0);
        }
        kf2 = kn; va = van; vb = vbn; S = Sn;
    }

    if (dq) {
        // tail chunk 40: d 1280..1295 = S rows 0..7 (already in S), V in va
        float p[8];
        #pragma unroll
        for (int r = 0; r < 8; ++r) p[r] = __builtin_amdgcn_exp2f(S[r]);
        unsigned P0 = cvtpk(p[0], p[1]);
        unsigned P1 = cvtpk(p[2], p[3]);
        unsigned P2 = cvtpk(p[4], p[5]);
        unsigned P3 = cvtpk(p[6], p[7]);
        u32x2 s02 = __builtin_amdgcn_permlane32_swap(P0, P2, false, false);
        u32x2 s13 = __builtin_amdgcn_permlane32_swap(P1, P3, false, false);
        u32x4 bw = {s02[0], s13[0], s02[1], s13[1]};
        frag8 pf = __builtin_bit_cast(frag8, bw);
        Oacc = __builtin_amdgcn_mfma_f32_32x32x16_bf16(va, pf, Oacc, 0, 0, 0);
        // publish partial O (regs 0..7) + partial lsum (reg 8)
        #pragma unroll
        for (int r = 0; r < 8; ++r) Lc[qw][r][lane] = Oacc[r];
        Lc[qw][8][lane] = Oacc[8];
    }
    __syncthreads();
    if (dq == 0) {
        #pragma unroll
        for (int r = 0; r < 8; ++r) Oacc[r] += Lc[qw][r][lane];
        float lsum = Oacc[8] + Lc[qw][8][lane];
        // lsum valid on hi==0 lanes (row 16); broadcast lo->hi
        u32x2 lb = __builtin_amdgcn_permlane32_swap(__float_as_uint(lsum),
                                                    __float_as_uint(lsum), false, false);
        float inv = frcp(__uint_as_float(lb[0]));
        if (qtok < HW) {
            short* An = (short*)A + ((size_t)n * HW + qtok) * CH + head * 16;
            // c = 4*hi + (r&3) + 8*(r>>2), r = 0..7
            int2 pk0 = pack4(Oacc[0] * inv, Oacc[1] * inv, Oacc[2] * inv, Oacc[3] * inv);
            int2 pk1 = pack4(Oacc[4] * inv, Oacc[5] * inv, Oacc[6] * inv, Oacc[7] * inv);
            *(int2*)&An[hi * 4] = pk0;
            *(int2*)&An[8 + hi * 4] = pk1;
        }
    }
}

extern "C" void kernel_launch(void* const* d_in, const int* in_sizes, int n_in,
                              void* d_out, int out_size, void* d_ws, size_t ws_size,
                              hipStream_t stream) {
    char* ws = (char*)d_ws;
    bf16*  Wst  = (bf16*)(ws + 256);          // 327680 bf16
    float* Bst  = (float*)(ws + 655616);      // 768 f32
    bf16*  XT   = (bf16*)(ws + 1048576);      // channel-last [n][1296][128]
    bf16*  Zb   = XT + TT;
    bf16*  Qb   = Zb + TT;                    // head-grouped [n][8][1296][16]
    bf16*  Kb   = Qb + TT;
    bf16*  Vb   = Kb + TT;                    // channel-first [n][128][1296]
    bf16*  Ab   = Vb + TT;
    bf16*  Hb   = Ab + TT;                    // ~19.6 MB total

    k_prep<<<1284, 256, 0, stream>>>(d_in[1], d_in[3], d_in[5], d_in[6], d_in[7],
                                     d_in[8], d_in[12], d_in[14], d_in[16],
                                     d_in[2], d_in[4], d_in[9], d_in[13], d_in[15], d_in[17],
                                     Wst, Bst);
    // n on blockIdx.x (gridDim.x == 8): linear wg id % 8 == n -> per-batch XCD locality
    k_inm<<<dim3(8, 41, 4), 256, 0, stream>>>(d_in[0], d_in[1], Wst, Bst, XT);
    k_mm<0><<<dim3(8, 41, 4), 256, 0, stream>>>(XT, nullptr, Wst + 16384, Bst + 128,
                                                Zb, nullptr, nullptr);
    k_mm<1><<<dim3(8, 41, 12), 256, 0, stream>>>(Zb, nullptr, Wst + 163840, nullptr,
                                                 Qb, Kb, Vb);
    k_attn<<<dim3(8, 11, 8), 512, 0, stream>>>(Qb, Kb, Vb, Ab);
    k_mm<2><<<dim3(8, 41, 4), 256, 0, stream>>>(Zb, Ab, Wst + 212992, Bst + 256,
                                                Hb, nullptr, nullptr);
    k_outm<<<dim3(8, 41, 2), 256, 0, stream>>>(Hb, Wst + 311296, Bst + 640, d_out, d_in[1]);
}

// Round 4
// 193.931 us; speedup vs baseline: 1.1316x; 1.1316x over previous
//
#include <hip/hip_runtime.h>
#include <hip/hip_bf16.h>
#include <math.h>

typedef __hip_bfloat16 bf16;
typedef __attribute__((ext_vector_type(8))) short frag8;
typedef __attribute__((ext_vector_type(4))) float f32x4;
typedef __attribute__((ext_vector_type(16))) float f32x16;
typedef __attribute__((ext_vector_type(2))) unsigned int u32x2;
typedef __attribute__((ext_vector_type(4))) unsigned int u32x4;

#define HW  1296
#define CH  128
#define TT  1327104   // 8 * 1296 * 128

__device__ __forceinline__ float b2f(bf16 v) { return __bfloat162float(v); }
__device__ __forceinline__ float bits2f(unsigned short u) {
    return __uint_as_float(((unsigned)u) << 16);
}
__device__ __forceinline__ float frcp(float x) { return __builtin_amdgcn_rcpf(x); }
__device__ __forceinline__ float fsigm(float x) { return frcp(1.0f + __expf(-x)); }
__device__ __forceinline__ float ftanh(float x) {
    float xc = fminf(15.0f, fmaxf(-15.0f, x));
    float e = __expf(2.0f * xc);
    return (e - 1.0f) * frcp(e + 1.0f);
}
// round-half-up f32->bf16 pair pack: 2 adds + 1 v_perm
__device__ __forceinline__ int packrh(float a, float b) {
    unsigned ua = __float_as_uint(a) + 0x8000u;
    unsigned ub = __float_as_uint(b) + 0x8000u;
    return (int)__builtin_amdgcn_perm(ub, ua, 0x07060302);
}
__device__ __forceinline__ int2 pack4(float a, float b, float c, float d) {
    int2 r; r.x = packrh(a, b); r.y = packrh(c, d); return r;
}
// packed RNE f32 pair -> bf16x2 in one VALU op
__device__ __forceinline__ unsigned cvtpk(float a, float b) {
    unsigned r;
    asm("v_cvt_pk_bf16_f32 %0, %1, %2" : "=v"(r) : "v"(a), "v"(b));
    return r;
}

// inline wave-uniform dtype detection (256 probe elems of w_in)
__device__ __forceinline__ int detect_f32(const void* w) {
    const short4* p = (const short4*)w;
    short4 v = p[threadIdx.x & 63];
    int bad = 0;
    #pragma unroll
    for (int j = 0; j < 4; ++j) {
        float f = bits2f(((const unsigned short*)&v)[j]);
        if (!(fabsf(f) <= 100.0f)) bad = 1;   // catches NaN/Inf too
    }
    return __any(bad) ? 1 : 0;
}

// ---------------- weight prep ----------------
// Wst (bf16): w_in[128o][128i]@0 | wconvT[9tap][128o][128r]@16384 |
//   wqkv[384o][128i]@163840 | wg[3][128o][256k]@212992 | wout[128o][128i]@311296
// Bst f32[768]: in@0 conv@128 i@256 g@384 o@512 out@640
// NOTE: wq rows (idx 163840..180223) are pre-scaled by log2(e) so attention
// can use exp2 directly (Qb feeds only k_attn).
__global__ __launch_bounds__(256) void k_prep(
    const void* w_in, const void* w_conv, const void* wq, const void* wk, const void* wv,
    const void* w_i, const void* w_g, const void* w_o, const void* w_out,
    const void* b_in, const void* b_conv, const void* b_i, const void* b_g,
    const void* b_o, const void* b_out,
    bf16* __restrict__ Wdst, float* __restrict__ Bdst)
{
    int idx = blockIdx.x * 256 + threadIdx.x;
    const int f = detect_f32(w_in);
    if (idx < 327680) {
        const void* src; int si;
        if (idx < 16384)       { src = w_in; si = idx; }   // native [o][i]
        else if (idx < 163840) { int j = idx - 16384; int tap = j >> 14, rem = j & 16383;
                                 int o = rem >> 7, r = rem & 127;
                                 src = w_conv; si = o * 2304 + r * 9 + tap; }
        else if (idx < 212992) { int j = idx - 163840; int o = j >> 7, i = j & 127;
                                 int ws_ = o >> 7;
                                 src = ws_ == 0 ? wq : ws_ == 1 ? wk : wv;
                                 si = (o & 127) * 128 + i; }
        else if (idx < 311296) { int j = idx - 212992; int g = j >> 15, rem = j & 32767;
                                 int o = rem >> 8, k = rem & 255;
                                 src = g == 0 ? w_i : g == 1 ? w_g : w_o; si = o * 256 + k; }
        else                   { int j = idx - 311296; int o = j >> 7, i = j & 127;
                                 src = w_out; si = o * 128 + i; }
        float v = f ? ((const float*)src)[si] : b2f(((const bf16*)src)[si]);
        if (idx >= 163840 && idx < 180224) v *= 1.4426950408889634f;  // wq * log2(e)
        Wdst[idx] = __float2bfloat16(v);
    } else if (idx < 327680 + 768) {
        int j = idx - 327680; int b = j >> 7, e = j & 127;
        const void* src = b == 0 ? b_in : b == 1 ? b_conv : b == 2 ? b_i
                        : b == 3 ? b_g : b == 4 ? b_o : b_out;
        Bdst[j] = f ? ((const float*)src)[e] : b2f(((const bf16*)src)[e]);
    }
}

// ---------------- k_inm: fused transpose + MFMA GEMM + tanh ----------------
// grid (8 n, 41 ptile, 4 otile) — n on blockIdx.x => all blocks of a batch land
// on one XCD (linear wg id % 8 == n), keeping the activation slab in one L2.
__global__ __launch_bounds__(256) void k_inm(const void* __restrict__ x,
                                             const void* __restrict__ wraw,
                                             const bf16* __restrict__ Wm,   // [o][i]
                                             const float* __restrict__ bias,
                                             bf16* __restrict__ XT) {
    __shared__ short Xl[32][132];
    const int tid = threadIdx.x, wave = tid >> 6, lane = tid & 63;
    const int quad = lane >> 4, l16 = lane & 15;
    const int n = blockIdx.x;
    const int pbase = blockIdx.y * 32;
    const int obase = blockIdx.z * 32 + (wave & 1) * 16;
    const int pstrip = (wave >> 1) * 16;
    const int f = detect_f32(wraw);

    #pragma unroll
    for (int rep = 0; rep < 4; ++rep) {
        int u = tid + rep * 256;
        int i = u >> 3;
        int p4 = (u & 7) * 4;
        int p = pbase + p4;
        short4 s = {0, 0, 0, 0};
        if (p < HW) {
            size_t gi = (size_t)n * CH * HW + (size_t)i * HW + p;
            if (f) {
                float4 fv = *(const float4*)((const float*)x + gi);
                int2 pk = pack4(fv.x, fv.y, fv.z, fv.w);
                s = *(short4*)&pk;
            } else {
                s = *(const short4*)((const bf16*)x + gi);
            }
        }
        Xl[p4 + 0][i] = s.x; Xl[p4 + 1][i] = s.y;
        Xl[p4 + 2][i] = s.z; Xl[p4 + 3][i] = s.w;
    }
    __syncthreads();

    const int pl = pstrip + l16;
    f32x4 acc = {0.f, 0.f, 0.f, 0.f};
    #pragma unroll
    for (int kc = 0; kc < 4; ++kc) {
        int k = kc * 32 + quad * 8;
        short4 b0 = *(const short4*)&Xl[pl][k];
        short4 b1 = *(const short4*)&Xl[pl][k + 4];
        frag8 bf = {b0.x, b0.y, b0.z, b0.w, b1.x, b1.y, b1.z, b1.w};
        frag8 wf = *(const frag8*)&Wm[(obase + l16) * CH + k];
        acc = __builtin_amdgcn_mfma_f32_16x16x32_bf16(wf, bf, acc, 0, 0, 0);
    }

    int p = pbase + pstrip + l16;
    if (p < HW) {
        int og = obase + quad * 4;
        int2 pk = pack4(ftanh(acc[0] + bias[og + 0]), ftanh(acc[1] + bias[og + 1]),
                        ftanh(acc[2] + bias[og + 2]), ftanh(acc[3] + bias[og + 3]));
        *(int2*)((short*)XT + ((size_t)n * HW + p) * CH + og) = pk;
    }
}

// ---------------- MFMA GEMM family, 64p x 32o blocks (wave = 16o x 32p, 2 p-frags) ------
// grid (8 n, 21 ptile, z otile) — XCD-local per batch. Two independent p-frag
// MFMA chains per wave = the ILP that keeps latency hidden (round-3 p-split
// to 1 chain regressed 40->50us with everything idle).
// MODE 0: CONV (9 taps, unrolled)  MODE 1: QKV (Q,K head-grouped; V channel-first via swap)
template<int MODE>
__global__ __launch_bounds__(256) void k_mm(
    const bf16* __restrict__ Act, const bf16* __restrict__ Act2,
    const bf16* __restrict__ Wm, const float* __restrict__ bias,
    bf16* __restrict__ o0, bf16* __restrict__ o1, bf16* __restrict__ o2)
{
    constexpr int KW  = 128;
    const int tid = threadIdx.x, wave = tid >> 6, lane = tid & 63;
    const int quad = lane >> 4, l16 = lane & 15;
    const int ostrip = wave & 1, pstrip = wave >> 1;
    const int n = blockIdx.x;
    const int obase = blockIdx.z * 32 + ostrip * 16;
    const int pbase = blockIdx.y * 64 + pstrip * 32;
    const bf16* actn = Act + (size_t)n * HW * CH;
    const bool vtile = (MODE == 1) && (obase >= 256);   // wave-uniform

    const int p1 = pbase + l16, p2 = pbase + 16 + l16;
    const bool p1ok = p1 < HW, p2ok = p2 < HW;

    frag8 zf = {0, 0, 0, 0, 0, 0, 0, 0};
    f32x4 acc[2];
    acc[0] = (f32x4){0.f, 0.f, 0.f, 0.f};
    acc[1] = (f32x4){0.f, 0.f, 0.f, 0.f};

    if (MODE == 0) {
        const int h1 = p1 / 36, w1 = p1 - h1 * 36;
        const int h2 = p2 / 36, w2 = p2 - h2 * 36;
        #pragma unroll
        for (int tap = 0; tap < 9; ++tap) {
            int dy = tap / 3 - 1, dx = tap - (tap / 3) * 3 - 1;
            bool ok1 = p1ok && (unsigned)(h1 + dy) < 36u && (unsigned)(w1 + dx) < 36u;
            bool ok2 = p2ok && (unsigned)(h2 + dy) < 36u && (unsigned)(w2 + dx) < 36u;
            int sh = dy * 36 + dx;
            const bf16* a1 = actn + (size_t)(p1 + sh) * CH + quad * 8;
            const bf16* a2 = actn + (size_t)(p2 + sh) * CH + quad * 8;
            const bf16* wp = Wm + tap * 16384 + (obase + l16) * CH + quad * 8;
            #pragma unroll
            for (int kc = 0; kc < 4; ++kc) {
                frag8 bf1 = zf, bf2 = zf;
                if (ok1) bf1 = *(const frag8*)&a1[kc * 32];
                if (ok2) bf2 = *(const frag8*)&a2[kc * 32];
                frag8 wf = *(const frag8*)&wp[kc * 32];
                acc[0] = __builtin_amdgcn_mfma_f32_16x16x32_bf16(wf, bf1, acc[0], 0, 0, 0);
                acc[1] = __builtin_amdgcn_mfma_f32_16x16x32_bf16(wf, bf2, acc[1], 0, 0, 0);
            }
        }
    } else {
        #pragma unroll
        for (int kc = 0; kc < KW / 32; ++kc) {
            int ko = kc * 32 + quad * 8;
            frag8 bf1 = zf, bf2 = zf;
            if (p1ok) bf1 = *(const frag8*)&actn[(size_t)p1 * CH + ko];
            if (p2ok) bf2 = *(const frag8*)&actn[(size_t)p2 * CH + ko];
            const bf16* wp = Wm + (obase + l16) * KW + kc * 32 + quad * 8;
            frag8 wf = *(const frag8*)wp;
            if (vtile) {
                acc[0] = __builtin_amdgcn_mfma_f32_16x16x32_bf16(bf1, wf, acc[0], 0, 0, 0);
                acc[1] = __builtin_amdgcn_mfma_f32_16x16x32_bf16(bf2, wf, acc[1], 0, 0, 0);
            } else {
                acc[0] = __builtin_amdgcn_mfma_f32_16x16x32_bf16(wf, bf1, acc[0], 0, 0, 0);
                acc[1] = __builtin_amdgcn_mfma_f32_16x16x32_bf16(wf, bf2, acc[1], 0, 0, 0);
            }
        }
    }

    // ---- epilogue ----
    if (vtile) {
        int ov = (obase - 256) + l16;
        #pragma unroll
        for (int pt = 0; pt < 2; ++pt) {
            int p4 = pbase + pt * 16 + quad * 4;
            if (p4 >= HW) continue;
            int2 pk = pack4(acc[pt][0], acc[pt][1], acc[pt][2], acc[pt][3]);
            *(int2*)((short*)o2 + ((size_t)n * CH + ov) * HW + p4) = pk;
        }
        return;
    }
    const int og = obase + quad * 4;
    #pragma unroll
    for (int pt = 0; pt < 2; ++pt) {
        int p = pbase + pt * 16 + l16;
        if (p >= HW) continue;
        size_t rowoff = ((size_t)n * HW + p) * CH;
        if (MODE == 0) {
            int2 pk = pack4(acc[pt][0] + bias[og + 0], acc[pt][1] + bias[og + 1],
                            acc[pt][2] + bias[og + 2], acc[pt][3] + bias[og + 3]);
            *(int2*)((short*)o0 + rowoff + og) = pk;
        } else {
            int which = og >> 7, ol = og & 127;
            bf16* dst = which == 0 ? o0 : o1;
            size_t di = (((size_t)n * 8 + (ol >> 4)) * HW + p) * 16 + (ol & 15);
            int2 pk = pack4(acc[pt][0], acc[pt][1], acc[pt][2], acc[pt][3]);
            *(int2*)((short*)dst + di) = pk;
        }
    }
}

// ---------------- k_cell: gates GEMM + LSTM cell + FUSED out-projection ----------------
// grid (8 n, 41 ptile). Block = 256 thr = 4 waves; 32p x 128o per block.
// Phase 1 (gates): wave w owns o-range [w*32, w*32+32) x all 32p
//   (2 o-frags x 3 gates x 2 p-frags = 12 accs). K=256 over cat(z, a).
// Phase 2 (cell): h = o*tanh(i*g) -> LDS Hl[32][136] (b64-aligned rows).
// Phase 3 (out): wave w = (ptile = w&1, ohalf = w>>1): 16p x 64o via k_outm's
//   verified operand scheme (A = h-row frag, B = W_out row frag -> channel-first
//   store). Removes the k_outm launch + the Hb global round-trip entirely.
__global__ __launch_bounds__(256) void k_cell(
    const bf16* __restrict__ Zb, const bf16* __restrict__ Ab,
    const bf16* __restrict__ Wg, const float* __restrict__ bg,
    const bf16* __restrict__ Wo, const float* __restrict__ bo,
    void* __restrict__ out, const void* __restrict__ wraw)
{
    __shared__ short Hl[32][136];   // row stride 272B: 16B-aligned, 2-way banks max
    const int tid = threadIdx.x, w = tid >> 6, lane = tid & 63;
    const int quad = lane >> 4, l16 = lane & 15;
    const int n = blockIdx.x;
    const int pbase = blockIdx.y * 32;
    const int f32f = detect_f32(wraw);
    const bf16* zn = Zb + (size_t)n * HW * CH;
    const bf16* an = Ab + (size_t)n * HW * CH;

    const int obase = w * 32;
    const int p1 = pbase + l16, p2 = pbase + 16 + l16;
    const bool p1ok = p1 < HW, p2ok = p2 < HW;

    frag8 zf = {0, 0, 0, 0, 0, 0, 0, 0};
    f32x4 acc[3][2][2];
    #pragma unroll
    for (int g = 0; g < 3; ++g)
        #pragma unroll
        for (int of = 0; of < 2; ++of) {
            acc[g][of][0] = (f32x4){0.f, 0.f, 0.f, 0.f};
            acc[g][of][1] = (f32x4){0.f, 0.f, 0.f, 0.f};
        }

    #pragma unroll
    for (int kc = 0; kc < 8; ++kc) {
        const bf16* src = (kc >= 4) ? an : zn;
        int ko = (kc & 3) * 32 + quad * 8;
        frag8 b1 = zf, b2 = zf;
        if (p1ok) b1 = *(const frag8*)&src[(size_t)p1 * CH + ko];
        if (p2ok) b2 = *(const frag8*)&src[(size_t)p2 * CH + ko];
        #pragma unroll
        for (int g = 0; g < 3; ++g) {
            #pragma unroll
            for (int of = 0; of < 2; ++of) {
                const bf16* wp = Wg + g * 32768 + (obase + of * 16 + l16) * 256
                               + kc * 32 + quad * 8;
                frag8 wf = *(const frag8*)wp;
                acc[g][of][0] = __builtin_amdgcn_mfma_f32_16x16x32_bf16(wf, b1, acc[g][of][0], 0, 0, 0);
                acc[g][of][1] = __builtin_amdgcn_mfma_f32_16x16x32_bf16(wf, b2, acc[g][of][1], 0, 0, 0);
            }
        }
    }

    // cell nonlinearity -> LDS h tile (rows for p >= HW hold finite garbage,
    // consumed only by discarded outputs)
    #pragma unroll
    for (int of = 0; of < 2; ++of) {
        #pragma unroll
        for (int pt = 0; pt < 2; ++pt) {
            int og = obase + of * 16 + quad * 4;
            int pl = pt * 16 + l16;
            float hv[4];
            #pragma unroll
            for (int r = 0; r < 4; ++r) {
                int o = og + r;
                float iv = fsigm(acc[0][of][pt][r] + bg[o]);
                float gv = ftanh(acc[1][of][pt][r] + bg[128 + o]);
                float ov = fsigm(acc[2][of][pt][r] + bg[256 + o]);
                hv[r] = ov * ftanh(iv * gv);
            }
            *(int2*)&Hl[pl][og] = pack4(hv[0], hv[1], hv[2], hv[3]);
        }
    }
    __syncthreads();

    // out-projection: wave -> (ptile, ohalf); 4 o-frags x 4 kc = 16 MFMAs
    const int ptile = w & 1, ohalf = w >> 1;
    const int pa = ptile * 16 + l16;
    f32x4 oc[4];
    #pragma unroll
    for (int of = 0; of < 4; ++of) oc[of] = (f32x4){0.f, 0.f, 0.f, 0.f};
    #pragma unroll
    for (int kc = 0; kc < 4; ++kc) {
        int k = kc * 32 + quad * 8;
        short4 h0 = *(const short4*)&Hl[pa][k];
        short4 h1 = *(const short4*)&Hl[pa][k + 4];
        frag8 af = {h0.x, h0.y, h0.z, h0.w, h1.x, h1.y, h1.z, h1.w};
        #pragma unroll
        for (int of = 0; of < 4; ++of) {
            const bf16* wp = Wo + (size_t)(ohalf * 64 + of * 16 + l16) * CH + k;
            frag8 bw = *(const frag8*)wp;
            oc[of] = __builtin_amdgcn_mfma_f32_16x16x32_bf16(af, bw, oc[of], 0, 0, 0);
        }
    }
    int p4 = pbase + ptile * 16 + quad * 4;
    if (p4 < HW) {
        #pragma unroll
        for (int of = 0; of < 4; ++of) {
            int o = ohalf * 64 + of * 16 + l16;
            float bv = bo[o];
            size_t di = ((size_t)n * CH + o) * HW + p4;
            if (f32f) {
                float4 fv = {oc[of][0] + bv, oc[of][1] + bv, oc[of][2] + bv, oc[of][3] + bv};
                *(float4*)&((float*)out)[di] = fv;
            } else {
                int2 pk = pack4(oc[of][0] + bv, oc[of][1] + bv, oc[of][2] + bv, oc[of][3] + bv);
                *(int2*)&((short*)out)[di] = pk;
            }
        }
    }
}

// ---------------- MFMA flash attention v7: 32x32x16, d-split x2, S-pipelined ----------------
// grid (8 n, 11 qtile, 8 head), 512 threads = 8 waves: qw = w&3 (32 q each),
// dq = w>>2 (d-halves: chunks 0..19 / 20..40). Softmax has no running max, so
// partial O = sum P*V and L = sum P over disjoint d-ranges combine additively
// (LDS, one barrier). Per chunk the NEXT chunk's QK^T MFMA issues before the
// current chunk's exp2/pack, and K is prefetched 2 chunks deep — the serial
// chain per chunk is VALU+PV only.
// S layout (m74/m101): col=q=lane&31, row=d_local=(r&3)+8*(r>>2)+4*(lane>>5).
// lsum comes free: V A-operand row c==16 is all-ones -> Oacc[8] = sum_d P[d][q].
// wq pre-scaled by log2(e) in k_prep -> P = exp2(S) directly.
__global__ __launch_bounds__(512) void k_attn(const bf16* __restrict__ Qg,
                                              const bf16* __restrict__ Kg,
                                              const bf16* __restrict__ Vcf,
                                              bf16* __restrict__ A) {
    __shared__ float Lc[4][9][64];   // [qw][acc reg 0..7 + lsum][lane] — conflict-free

    const int tid = threadIdx.x;
    const int w = tid >> 6, lane = tid & 63;
    const int l32 = lane & 31, hi = lane >> 5;
    const int qw = w & 3, dq = w >> 2;
    const int n = blockIdx.x;
    const int head = blockIdx.z;
    const int qb = blockIdx.y * 128 + qw * 32;
    const int qtok = qb + l32;

    const short* Qh = (const short*)Qg + ((size_t)(n * 8 + head)) * HW * 16;
    const short* Kh = (const short*)Kg + ((size_t)(n * 8 + head)) * HW * 16;
    const short* Vh = (const short*)Vcf + ((size_t)n * CH + head * 16) * HW;

    // Q fragment (B operand): B[c = 8*hi + j][q = l32]; OOB q-waves compute
    // garbage on qf=0 but must NOT exit (barrier below).
    frag8 qf = {0, 0, 0, 0, 0, 0, 0, 0};
    if (qtok < HW) qf = *(const frag8*)&Qh[(size_t)qtok * 16 + hi * 8];

    // V A-operand fill: row c==16 -> ones (lsum row), rows 17..31 -> zero
    const short one = (short)0x3F80;
    const frag8 vones = {one, one, one, one, one, one, one, one};
    const frag8 vzero = {0, 0, 0, 0, 0, 0, 0, 0};
    const frag8 vfill = (l32 == 16) ? vones : vzero;
    const bool vload = l32 < 16;
    const short* Vrow = Vh + (size_t)(vload ? l32 : 0) * HW;

    const f32x16 zero16 = {};
    f32x16 Oacc = {};

    auto KLD = [&](int dd) -> frag8 {
        return *(const frag8*)&Kh[(size_t)(dd + l32) * 16 + hi * 8];
    };
    auto VLD = [&](int dd) -> frag8 {
        return vload ? *(const frag8*)&Vrow[dd + hi * 8] : vfill;
    };

    const int c0 = dq ? 20 : 0;       // chunk range: dq0 -> 0..19, dq1 -> 20..39 (+tail 40)
    frag8 kf  = KLD(c0 * 32);         // K(chunk c0)
    frag8 kf2 = KLD(c0 * 32 + 32);    // K(chunk c0+1)
    frag8 va  = VLD(c0 * 32);
    frag8 vb  = VLD(c0 * 32 + 16);
    f32x16 S = __builtin_amdgcn_mfma_f32_32x32x16_bf16(kf, qf, zero16, 0, 0, 0);

    // 20 chunks per wave. Prefetch: K 2-deep, V 1-deep. Reads past logical end
    // stay inside the workspace (spill into adjacent buffers, values unused).
    for (int it = 0; it < 20; ++it) {
        const int d0 = (c0 + it) * 32;
        frag8 kn  = KLD(d0 + 64);
        frag8 van = VLD(d0 + 32);
        frag8 vbn = VLD(d0 + 48);
        // issue next chunk's QK^T early; its latency hides under the VALU below.
        // dq1 it=19: this computes the tail chunk's S (rows 0..7 valid) — used below.
        f32x16 Sn = __builtin_amdgcn_mfma_f32_32x32x16_bf16(kf2, qf, zero16, 0, 0, 0);

        float p[16];
        #pragma unroll
        for (int r = 0; r < 16; ++r) p[r] = __builtin_amdgcn_exp2f(S[r]);

        #pragma unroll
        for (int hh = 0; hh < 2; ++hh) {
            unsigned P0 = cvtpk(p[hh * 8 + 0], p[hh * 8 + 1]);
            unsigned P1 = cvtpk(p[hh * 8 + 2], p[hh * 8 + 3]);
            unsigned P2 = cvtpk(p[hh * 8 + 4], p[hh * 8 + 5]);
            unsigned P3 = cvtpk(p[hh * 8 + 6], p[hh * 8 + 7]);
            u32x2 s02 = __builtin_amdgcn_permlane32_swap(P0, P2, false, false);
            u32x2 s13 = __builtin_amdgcn_permlane32_swap(P1, P3, false, false);
            u32x4 bw = {s02[0], s13[0], s02[1], s13[1]};
            frag8 pf = __builtin_bit_cast(frag8, bw);
            Oacc = __builtin_amdgcn_mfma_f32_32x32x16_bf16(hh ? vb : va, pf, Oacc, 0, 0, 0);
        }
        kf2 = kn; va = van; vb = vbn; S = Sn;
    }

    if (dq) {
        // tail chunk 40: d 1280..1295 = S rows 0..7 (already in S), V in va
        float p[8];
        #pragma unroll
        for (int r = 0; r < 8; ++r) p[r] = __builtin_amdgcn_exp2f(S[r]);
        unsigned P0 = cvtpk(p[0], p[1]);
        unsigned P1 = cvtpk(p[2], p[3]);
        unsigned P2 = cvtpk(p[4], p[5]);
        unsigned P3 = cvtpk(p[6], p[7]);
        u32x2 s02 = __builtin_amdgcn_permlane32_swap(P0, P2, false, false);
        u32x2 s13 = __builtin_amdgcn_permlane32_swap(P1, P3, false, false);
        u32x4 bw = {s02[0], s13[0], s02[1], s13[1]};
        frag8 pf = __builtin_bit_cast(frag8, bw);
        Oacc = __builtin_amdgcn_mfma_f32_32x32x16_bf16(va, pf, Oacc, 0, 0, 0);
        // publish partial O (regs 0..7) + partial lsum (reg 8)
        #pragma unroll
        for (int r = 0; r < 8; ++r) Lc[qw][r][lane] = Oacc[r];
        Lc[qw][8][lane] = Oacc[8];
    }
    __syncthreads();
    if (dq == 0) {
        #pragma unroll
        for (int r = 0; r < 8; ++r) Oacc[r] += Lc[qw][r][lane];
        float lsum = Oacc[8] + Lc[qw][8][lane];
        // lsum valid on hi==0 lanes (row 16); broadcast lo->hi
        u32x2 lb = __builtin_amdgcn_permlane32_swap(__float_as_uint(lsum),
                                                    __float_as_uint(lsum), false, false);
        float inv = frcp(__uint_as_float(lb[0]));
        if (qtok < HW) {
            short* An = (short*)A + ((size_t)n * HW + qtok) * CH + head * 16;
            // c = 4*hi + (r&3) + 8*(r>>2), r = 0..7
            int2 pk0 = pack4(Oacc[0] * inv, Oacc[1] * inv, Oacc[2] * inv, Oacc[3] * inv);
            int2 pk1 = pack4(Oacc[4] * inv, Oacc[5] * inv, Oacc[6] * inv, Oacc[7] * inv);
            *(int2*)&An[hi * 4] = pk0;
            *(int2*)&An[8 + hi * 4] = pk1;
        }
    }
}

extern "C" void kernel_launch(void* const* d_in, const int* in_sizes, int n_in,
                              void* d_out, int out_size, void* d_ws, size_t ws_size,
                              hipStream_t stream) {
    char* ws = (char*)d_ws;
    bf16*  Wst  = (bf16*)(ws + 256);          // 327680 bf16
    float* Bst  = (float*)(ws + 655616);      // 768 f32
    bf16*  XT   = (bf16*)(ws + 1048576);      // channel-last [n][1296][128]
    bf16*  Zb   = XT + TT;
    bf16*  Qb   = Zb + TT;                    // head-grouped [n][8][1296][16]
    bf16*  Kb   = Qb + TT;
    bf16*  Vb   = Kb + TT;                    // channel-first [n][128][1296]
    bf16*  Ab   = Vb + TT;                    // ~17 MB total

    k_prep<<<1284, 256, 0, stream>>>(d_in[1], d_in[3], d_in[5], d_in[6], d_in[7],
                                     d_in[8], d_in[12], d_in[14], d_in[16],
                                     d_in[2], d_in[4], d_in[9], d_in[13], d_in[15], d_in[17],
                                     Wst, Bst);
    // n on blockIdx.x (gridDim.x == 8): linear wg id % 8 == n -> per-batch XCD locality
    k_inm<<<dim3(8, 41, 4), 256, 0, stream>>>(d_in[0], d_in[1], Wst, Bst, XT);
    k_mm<0><<<dim3(8, 21, 4), 256, 0, stream>>>(XT, nullptr, Wst + 16384, Bst + 128,
                                                Zb, nullptr, nullptr);
    k_mm<1><<<dim3(8, 21, 12), 256, 0, stream>>>(Zb, nullptr, Wst + 163840, nullptr,
                                                 Qb, Kb, Vb);
    k_attn<<<dim3(8, 11, 8), 512, 0, stream>>>(Qb, Kb, Vb, Ab);
    k_cell<<<dim3(8, 41), 256, 0, stream>>>(Zb, Ab, Wst + 212992, Bst + 256,
                                            Wst + 311296, Bst + 640, d_out, d_in[1]);
}